// Round 2
// baseline (3239.707 us; speedup 1.0000x reference)
//
#include <hip/hip_runtime.h>
#include <math.h>

// Problem constants (from reference)
#define BATCH   4096
#define NPUMP   4
#define NCH     100
#define NTOT    104          // NPUMP + NCH
#define NROWS   128          // padded rows (2 waves x 64 lanes)
#define RESPLEN 801
#define NSTEPS  499          // STEPS - 1

// dz = 50000/499
#define DZ_F   100.20040080160321f
#define HDZ_F  50.100200400801604f   // 0.5*dz
#define DZ6_F  16.700066800267202f   // dz/6

typedef float v2f __attribute__((ext_vector_type(2)));

__device__ __forceinline__ float gentry(float fi, float fj, const float* __restrict__ resp_s)
{
    // D[i][j] = f_j - f_i ; ratio[i][j] = f_i / f_j
    float D    = fj - fi;
    float ad   = fabsf(D);
    float fidx = ad / 5.0e10f;          // DF = FS/N_SAMP = 5e10
    int   i0   = (int)fidx;             // floor (fidx >= 0)
    i0 = i0 > (RESPLEN - 2) ? (RESPLEN - 2) : i0;
    float w  = fidx - (float)i0;
    float g  = resp_s[i0] * (1.0f - w) + resp_s[i0 + 1] * w;
    g = (D < 0.0f) ? -g : g;
    float ratio = fi / fj;
    float m  = fmaxf(1.0f, ratio);
    return g * m / 8e-11f;              // / EFFECTIVE_AREA
}

// 128 threads = 2 waves per block, one batch element per block, one row per lane.
// __launch_bounds__(128,3): cap ~170 VGPRs -> G (104) + pipeline slack, no AGPR round-trips.
__global__ __launch_bounds__(128, 3) void raman_kernel(
    const float* __restrict__ x,        // (BATCH, 8): [wl0..wl3, pw0..pw3]
    const float* __restrict__ resp,     // (801,)
    const float* __restrict__ sigwl,    // (100,)
    float* __restrict__ out)            // (BATCH, 100)
{
    const int b   = blockIdx.x;
    const int tid = threadIdx.x;        // 0..127 == row index (rows >=104 are dummies)

    __shared__ float resp_s[RESPLEN];
    __shared__ __align__(16) float fr_s[NROWS];
    __shared__ __align__(16) float Pb[2][NROWS];

    // stage raman response into LDS
    for (int i = tid; i < RESPLEN; i += NROWS) resp_s[i] = resp[i];

    const float* xb = x + b * 8;
    const int row = tid;

    // frequency of this row (dummy rows get lam=1 -> finite garbage, power stays 0)
    {
        float lam;
        if (row < NPUMP)      lam = xb[row];
        else if (row < NTOT)  lam = sigwl[row - NPUMP];
        else                  lam = 1.0f;
        fr_s[row] = 299792458.0f / lam;
    }
    __syncthreads();

    const float loss = 0.0002f * 0.23025850929940458f;   // 2e-4 * ln10/10

    // initial power: pumps |pw|, signals 1e-3, dummy rows 0
    float p;
    if (row < NPUMP)     p = fabsf(xb[NPUMP + row]);
    else if (row < NTOT) p = 0.001f;
    else                 p = 0.0f;

    // ---- build this row of G: 52 x float2 = 104 VGPRs ----
    v2f G[52];
    const float fi = fr_s[row];
    #pragma unroll
    for (int j = 0; j < 52; ++j) {
        v2f fj = ((const v2f*)fr_s)[j];
        v2f g;
        g.x = gentry(fi, fj.x, resp_s);
        g.y = gentry(fi, fj.y, resp_s);
        G[j] = g;
    }

    // ---- RK4 main loop ----
    // stage: write stage power, barrier, dot(G_row, P)
    auto stage = [&](float ps, int buf) -> float {
        Pb[buf][row] = ps;
        __syncthreads();
        const v2f* pv = (const v2f*)Pb[buf];
        v2f a0 = {0.f, 0.f}, a1 = {0.f, 0.f}, a2 = {0.f, 0.f}, a3 = {0.f, 0.f};
        #pragma unroll
        for (int j = 0; j < 52; j += 4) {
            a0 = __builtin_elementwise_fma(G[j + 0], pv[j + 0], a0);
            a1 = __builtin_elementwise_fma(G[j + 1], pv[j + 1], a1);
            a2 = __builtin_elementwise_fma(G[j + 2], pv[j + 2], a2);
            a3 = __builtin_elementwise_fma(G[j + 3], pv[j + 3], a3);
        }
        v2f s = (a0 + a1) + (a2 + a3);
        float dot = s.x + s.y;
        return (dot - loss) * ps;
    };

    for (int s = 0; s < NSTEPS; ++s) {
        float k1 = stage(p, 0);
        float k2 = stage(fmaf(HDZ_F, k1, p), 1);
        float k3 = stage(fmaf(HDZ_F, k2, p), 0);
        float k4 = stage(fmaf(DZ_F,  k3, p), 1);
        p = fmaf(DZ6_F, (k1 + 2.0f * k2) + (2.0f * k3 + k4), p);
    }

    // ---- output rows NPUMP..NTOT-1 -> (BATCH, 100) ----
    if (row >= NPUMP && row < NTOT) out[b * NCH + (row - NPUMP)] = p;
}

extern "C" void kernel_launch(void* const* d_in, const int* in_sizes, int n_in,
                              void* d_out, int out_size, void* d_ws, size_t ws_size,
                              hipStream_t stream)
{
    const float* x     = (const float*)d_in[0];
    const float* resp  = (const float*)d_in[1];
    const float* sigwl = (const float*)d_in[2];
    float* out = (float*)d_out;
    raman_kernel<<<BATCH, NROWS, 0, stream>>>(x, resp, sigwl, out);
}